// Round 17
// baseline (110.056 us; speedup 1.0000x reference)
//
#include <hip/hip_runtime.h>
#include <hip/hip_bf16.h>

// Problem constants: B=2, N=2048, C=1024, H=16, D=64  (head_dim)
// M = B*N = 4096 rows. qkv col layout: three*1024 + h*64 + d.

typedef __bf16 bf16x8 __attribute__((ext_vector_type(8)));
typedef float f32x4 __attribute__((ext_vector_type(4)));
typedef float f32x16 __attribute__((ext_vector_type(16)));
typedef unsigned short us8 __attribute__((ext_vector_type(8)));
typedef unsigned short us4 __attribute__((ext_vector_type(4)));

static __device__ __forceinline__ unsigned short f2b(float f) {
  __hip_bfloat16 h = __float2bfloat16(f);
  return __builtin_bit_cast(unsigned short, h);
}
static __device__ __forceinline__ float b2f(unsigned short u) {
  __hip_bfloat16 h = __builtin_bit_cast(__hip_bfloat16, u);
  return __bfloat162float(h);
}

#if __has_builtin(__builtin_amdgcn_exp2f)
static __device__ __forceinline__ float fast_exp2(float x) { return __builtin_amdgcn_exp2f(x); }
#else
static __device__ __forceinline__ float fast_exp2(float x) { return exp2f(x); }
#endif

// async global->LDS, 16B per lane. LDS dest = wave-uniform base + lane*16.
static __device__ __forceinline__ void async_copy16(void* lds, const void* g) {
  __builtin_amdgcn_global_load_lds(
      (const __attribute__((address_space(1))) void*)g,
      (__attribute__((address_space(3))) void*)lds, 16, 0, 0);
}

static __device__ __forceinline__ unsigned cvt_pk_bf16(float lo, float hi) {
  unsigned r;
  asm("v_cvt_pk_bf16_f32 %0, %1, %2" : "=v"(r) : "v"(lo), "v"(hi));
  return r;
}
static __device__ __forceinline__ void swap32(unsigned& x, unsigned& y) {
  asm("v_permlane32_swap_b32 %0, %1" : "+v"(x), "+v"(y));
}
static __device__ __forceinline__ float max3f(float a, float b, float c) {
  float d;
  asm("v_max3_f32 %0, %1, %2, %3" : "=v"(d) : "v"(a), "v"(b), "v"(c));
  return d;
}
// balanced max of 16 (5+2+1 ops, depth 3)
static __device__ __forceinline__ float vmax16(const f32x16& v) {
  float a = max3f(v[0], v[1], v[2]);
  float b = max3f(v[3], v[4], v[5]);
  float c = max3f(v[6], v[7], v[8]);
  float d = max3f(v[9], v[10], v[11]);
  float e = max3f(v[12], v[13], v[14]);
  float x = max3f(a, b, c);
  float y = max3f(d, e, v[15]);
  return fmaxf(x, y);
}

// ---------------------------------------------------------------- convert (all 3 inputs, 1 launch)
__global__ __launch_bounds__(256) void cvt_all(
    const float* __restrict__ x, const float* __restrict__ wqkv,
    const float* __restrict__ wproj, unsigned short* __restrict__ x_bf,
    unsigned short* __restrict__ wqkv_bf, unsigned short* __restrict__ wproj_bf) {
  int i = blockIdx.x * 256 + threadIdx.x;
  const float* src;
  unsigned short* dst;
  int off;
  if (i < 524288) {
    src = x; dst = x_bf; off = i;
  } else if (i < 917504) {
    src = wqkv; dst = wqkv_bf; off = i - 524288;
  } else {
    src = wproj; dst = wproj_bf; off = i - 917504;
  }
  const float4* p = reinterpret_cast<const float4*>(src) + (size_t)off * 2;
  float4 a = p[0], b = p[1];
  us8 v;
  v[0] = f2b(a.x); v[1] = f2b(a.y); v[2] = f2b(a.z); v[3] = f2b(a.w);
  v[4] = f2b(b.x); v[5] = f2b(b.y); v[6] = f2b(b.z); v[7] = f2b(b.w);
  reinterpret_cast<us8*>(dst)[off] = v;
}

// ---------------------------------------------------------------- QKV GEMM + LN + RoPE + V-transpose
// XCD-chunked block swizzle: 768 blocks, 96 consecutive tiles per XCD
// (= 4 complete A row-panels = 1MB A, L2-resident per XCD).
__global__ __launch_bounds__(256, 3) void gemm_qkv(
    const unsigned short* __restrict__ A,   // x_bf [4096][1024]
    const unsigned short* __restrict__ Bw,  // wqkv_bf [3072][1024]
    const float* __restrict__ fcos, const float* __restrict__ fsin,  // [2048][64]
    unsigned short* __restrict__ qo, unsigned short* __restrict__ ko,  // [32][2048][64]
    unsigned short* __restrict__ vt)  // [32][64][2048]
{
  __shared__ unsigned short a_sh[128 * 64];
  __shared__ unsigned short b_sh[128 * 64];
  const int tid = threadIdx.x;
  const int lane = tid & 63;
  const int w = tid >> 6;
  const int wr = w >> 1, wc = w & 1;
  const int l15 = lane & 15, l4 = lane >> 4;
  const int lin = blockIdx.y * 24 + blockIdx.x;
  const int swz = (lin & 7) * 96 + (lin >> 3);  // bijective (768 = 8*96)
  const int m0 = (swz / 24) * 128;
  const int n0 = (swz % 24) * 128;
  const int r8 = lane >> 3, c8 = lane & 7;
  const int K = 1024;

  f32x4 acc[4][4] = {};

  for (int k0 = 0; k0 < K; k0 += 64) {
#pragma unroll
    for (int p = 0; p < 8; ++p) {
      int s = p * 4 + w;
      if (s < 16) {
        int row = s * 8 + r8;
        async_copy16(&a_sh[s * 512],
                     &A[(size_t)(m0 + row) * K + k0 + ((c8 ^ (row & 7)) << 3)]);
      } else {
        int s2 = s - 16;
        int row = s2 * 8 + r8;
        async_copy16(&b_sh[s2 * 512],
                     &Bw[(size_t)(n0 + row) * K + k0 + ((c8 ^ (row & 7)) << 3)]);
      }
    }
    __syncthreads();
#pragma unroll
    for (int kk = 0; kk < 2; ++kk) {
      bf16x8 af[4], bfr[4];
#pragma unroll
      for (int mf = 0; mf < 4; ++mf) {
        int r = wr * 64 + mf * 16 + l15;
        af[mf] = *reinterpret_cast<const bf16x8*>(
            &a_sh[r * 64 + (((kk * 4 + l4) ^ (r & 7)) << 3)]);
      }
#pragma unroll
      for (int nf = 0; nf < 4; ++nf) {
        int r = wc * 64 + nf * 16 + l15;
        bfr[nf] = *reinterpret_cast<const bf16x8*>(
            &b_sh[r * 64 + (((kk * 4 + l4) ^ (r & 7)) << 3)]);
      }
#pragma unroll
      for (int mf = 0; mf < 4; ++mf)
#pragma unroll
        for (int nf = 0; nf < 4; ++nf)
          acc[mf][nf] = __builtin_amdgcn_mfma_f32_16x16x32_bf16(af[mf], bfr[nf], acc[mf][nf], 0, 0, 0);
    }
    __syncthreads();
  }

  // ---- fused epilogue ----
  const int colbase = n0 + wc * 64;       // head-aligned (64 | colbase)
  const int three = colbase >> 10;        // uniform per wave
  const int hh = (colbase >> 6) & 15;
  const int b_ = m0 >> 11;                // uniform per block (128 | 2048)
  const int nbase = (m0 & 2047) + wr * 64;
  unsigned short* ep = ((w < 2) ? a_sh : b_sh) + (w & 1) * 4096;  // 8KB/wave
  const int cch = lane & 7, rb2 = lane >> 3;

  if (three < 2) {
    const float sc = three ? 1.f : 0.18033688011112042f;  // q: D^-0.5 * log2(e)
#pragma unroll
    for (int mf = 0; mf < 4; ++mf) {
#pragma unroll
      for (int j = 0; j < 4; ++j) {
        float a0 = acc[mf][0][j], a1 = acc[mf][1][j];
        float a2 = acc[mf][2][j], a3 = acc[mf][3][j];
        float s1 = (a0 + a1) + (a2 + a3);
        float s2 = (a0 * a0 + a1 * a1) + (a2 * a2 + a3 * a3);
#pragma unroll
        for (int off = 8; off; off >>= 1) {
          s1 += __shfl_xor(s1, off);
          s2 += __shfl_xor(s2, off);
        }
        float mu = s1 * (1.f / 64.f);
        float inv = rsqrtf(s2 * (1.f / 64.f) - mu * mu + 1e-6f);
        int rloc = mf * 16 + l4 * 4 + j;  // row within wave block (0..63)
        int n = nbase + rloc;
        const float* cp = &fcos[(size_t)n * 64];
        const float* sp = &fsin[(size_t)n * 64];
#pragma unroll
        for (int nf = 0; nf < 4; ++nf) {
          int d = nf * 16 + l15;
          float tt = (acc[mf][nf][j] - mu) * inv;
          float tp = (acc[mf][nf ^ 2][j] - mu) * inv;  // partner d^32
          float r = sc * (tt * cp[d] + ((nf < 2) ? -tp : tp) * sp[d]);
          ep[rloc * 64 + ((((d >> 3) ^ (rloc & 7)) << 3) | (d & 7))] = f2b(r);
        }
      }
    }
    unsigned short* dst =
        (three ? ko : qo) + (size_t)(b_ * 16 + hh) * 2048 * 64;
#pragma unroll
    for (int i = 0; i < 8; ++i) {
      int row = i * 8 + rb2;
      us8 vd = *reinterpret_cast<const us8*>(
          &ep[row * 64 + ((cch ^ (row & 7)) << 3)]);
      *reinterpret_cast<us8*>(&dst[(size_t)(nbase + row) * 64 + cch * 8]) = vd;
    }
  } else {
    // v: stash as [d][n_local] (transpose), then coalesced store to vt[bh][d][n]
#pragma unroll
    for (int mf = 0; mf < 4; ++mf)
#pragma unroll
      for (int nf = 0; nf < 4; ++nf) {
        int d = nf * 16 + l15;
#pragma unroll
        for (int j = 0; j < 4; ++j) {
          int nl = mf * 16 + l4 * 4 + j;
          ep[d * 64 + ((((nl >> 3) ^ (d & 7)) << 3) | (nl & 7))] =
              f2b(acc[mf][nf][j]);
        }
      }
    unsigned short* dst = vt + (size_t)(b_ * 16 + hh) * 64 * 2048;
#pragma unroll
    for (int i = 0; i < 8; ++i) {
      int d = i * 8 + rb2;
      us8 vd = *reinterpret_cast<const us8*>(
          &ep[d * 64 + ((cch ^ (d & 7)) << 3)]);
      *reinterpret_cast<us8*>(&dst[(size_t)d * 2048 + nbase + cch * 8]) = vd;
    }
  }
}

// ---------------------------------------------------------------- proj GEMM
// 128x64 tile (grid 16x32 = 512 blocks = 2/CU). 4 waves 2x2; acc[4][2].
__global__ __launch_bounds__(256, 2) void gemm_proj(
    const unsigned short* __restrict__ A, const unsigned short* __restrict__ Bw,
    const float* __restrict__ bias, float* __restrict__ Cout,
    int M, int Nn, int K) {
  __shared__ unsigned short a_sh[128 * 64];
  __shared__ unsigned short b_sh[64 * 64];
  const int tid = threadIdx.x;
  const int lane = tid & 63;
  const int w = tid >> 6;
  const int wr = w >> 1, wc = w & 1;
  const int l15 = lane & 15, l4 = lane >> 4;
  const int m0 = blockIdx.y * 128;
  const int n0 = blockIdx.x * 64;
  const int r8 = lane >> 3, c8 = lane & 7;

  f32x4 acc[4][2] = {};

  for (int k0 = 0; k0 < K; k0 += 64) {
#pragma unroll
    for (int p = 0; p < 6; ++p) {
      int s = p * 4 + w;
      if (s < 16) {
        int row = s * 8 + r8;
        async_copy16(&a_sh[s * 512],
                     &A[(size_t)(m0 + row) * K + k0 + ((c8 ^ (row & 7)) << 3)]);
      } else {
        int s2 = s - 16;
        int row = s2 * 8 + r8;
        async_copy16(&b_sh[s2 * 512],
                     &Bw[(size_t)(n0 + row) * K + k0 + ((c8 ^ (row & 7)) << 3)]);
      }
    }
    __syncthreads();
#pragma unroll
    for (int kk = 0; kk < 2; ++kk) {
      bf16x8 af[4], bfr[2];
#pragma unroll
      for (int mf = 0; mf < 4; ++mf) {
        int r = wr * 64 + mf * 16 + l15;
        af[mf] = *reinterpret_cast<const bf16x8*>(
            &a_sh[r * 64 + (((kk * 4 + l4) ^ (r & 7)) << 3)]);
      }
#pragma unroll
      for (int nf = 0; nf < 2; ++nf) {
        int r = wc * 32 + nf * 16 + l15;
        bfr[nf] = *reinterpret_cast<const bf16x8*>(
            &b_sh[r * 64 + (((kk * 4 + l4) ^ (r & 7)) << 3)]);
      }
#pragma unroll
      for (int mf = 0; mf < 4; ++mf)
#pragma unroll
        for (int nf = 0; nf < 2; ++nf)
          acc[mf][nf] = __builtin_amdgcn_mfma_f32_16x16x32_bf16(af[mf], bfr[nf], acc[mf][nf], 0, 0, 0);
    }
    __syncthreads();
  }
#pragma unroll
  for (int mf = 0; mf < 4; ++mf)
#pragma unroll
    for (int nf = 0; nf < 2; ++nf) {
      int col = n0 + wc * 32 + nf * 16 + l15;
#pragma unroll
      for (int j = 0; j < 4; ++j) {
        int row = m0 + wr * 64 + mf * 16 + l4 * 4 + j;
        Cout[(size_t)row * Nn + col] = acc[mf][nf][j] + bias[col];
      }
    }
}

// ---------------------------------------------------------------- attention
// R16 config + MFMA row-sum: the softmax denominator sum_k P[k][q] is
// computed on the MATRIX pipe via oT2 += mfma32(A=ones, pB[mi], .) — every
// output row of oT2 equals the colsum, so lr = oT2[0] at epilogue (no per-sub
// 64-add chain, no epilogue shfl). Numerator and denominator now sum the SAME
// bf16-rounded P. Rescale touches only oT2[0].
__global__ __launch_bounds__(256, 2) void attn_kern(
    const unsigned short* __restrict__ Q,   // [B*H][2048][64]  (pre-scaled)
    const unsigned short* __restrict__ Kk,  // [B*H][2048][64]
    const unsigned short* __restrict__ Vt,  // [B*H][64][2048]
    unsigned short* __restrict__ O)         // [B][2048][1024]
{
  __shared__ unsigned short k_sh[2][128 * 64];
  __shared__ unsigned short v_sh[2][64 * 128];
  const int tid = threadIdx.x;
  const int lane = tid & 63;
  const int w = tid >> 6;
  const int l31 = lane & 31;
  const int H = lane >> 5;
  const int bid = blockIdx.x;
  const int wid = (bid & 7) * 64 + (bid >> 3);  // XCD swizzle: 4 bh per XCD
  const int qt = wid & 15;
  const int bh = wid >> 4;
  const int h = bh & 15, b = bh >> 4;
  const unsigned short* qb = Q + (size_t)bh * 2048 * 64;
  const unsigned short* kb = Kk + (size_t)bh * 2048 * 64;
  const unsigned short* vb = Vt + (size_t)bh * 64 * 2048;
  const int tok = qt * 128 + w * 32 + l31;

  // Q B-frags: lane holds Q[tok][c*16 + H*8 .. +7]
  bf16x8 qf[4];
#pragma unroll
  for (int c = 0; c < 4; ++c)
    qf[c] = *reinterpret_cast<const bf16x8*>(&qb[(size_t)tok * 64 + c * 16 + H * 8]);

  // all-ones A-fragment for the denominator mfma (compile-time constant)
  us8 ones_u;
#pragma unroll
  for (int j = 0; j < 8; ++j) ones_u[j] = 0x3F80;  // bf16 1.0
  const bf16x8 ones = __builtin_bit_cast(bf16x8, ones_u);

  f32x16 oT[2] = {};
  f32x16 oT2 = {};  // denominator accumulator; only element [0] is consumed
  float mr = -1e30f;

  const int r8 = lane >> 3, cc8 = lane & 7;    // K staging
  const int r4 = lane >> 4, cc16 = lane & 15;  // V staging
  // stage one 128-key tile: K 16 segs (8 rows x 128B), V^T 16 segs (4 rows x 256B)
#define ATTN_STAGE(KT, BUF)                                                           \
  {                                                                                   \
    _Pragma("unroll") for (int p = 0; p < 8; ++p) {                                   \
      int sseg = p * 4 + w;                                                           \
      if (sseg < 16) {                                                                \
        int row = sseg * 8 + r8;                                                      \
        async_copy16(&k_sh[BUF][sseg * 512],                                          \
                     &kb[(size_t)((KT) * 128 + row) * 64 + ((cc8 ^ (row & 7)) << 3)]);   \
      } else {                                                                        \
        int s2 = sseg - 16;                                                           \
        int row = s2 * 4 + r4;                                                        \
        async_copy16(&v_sh[BUF][s2 * 512],                                            \
                     &vb[(size_t)row * 2048 + (KT) * 128 + ((cc16 ^ (row & 7)) << 3)]);  \
      }                                                                               \
    }                                                                                 \
  }

  ATTN_STAGE(0, 0);
  __syncthreads();

#pragma unroll 2
  for (int kt = 0; kt < 16; ++kt) {
    const int cur = kt & 1;  // compile-time under unroll-2 -> addresses hoist
    if (kt < 15) ATTN_STAGE(kt + 1, cur ^ 1);

#pragma unroll
    for (int sub = 0; sub < 2; ++sub) {
      // S^T[k][q] for this 64-key substep, accumulate over d (4 chunks of 16)
      f32x16 sT[2] = {};
#pragma unroll
      for (int c = 0; c < 4; ++c) {
        int ch0 = 2 * c + H;
#pragma unroll
        for (int t = 0; t < 2; ++t) {
          int r = (sub * 2 + t) * 32 + l31;
          bf16x8 ka = *reinterpret_cast<const bf16x8*>(
              &k_sh[cur][r * 64 + ((ch0 ^ (r & 7)) << 3)]);
          sT[t] = __builtin_amdgcn_mfma_f32_32x32x16_bf16(ka, qf[c], sT[t], 0, 0, 0);
        }
      }
      // online softmax (exp2 domain); defer-rescale THR=8
      float tmax = fmaxf(vmax16(sT[0]), vmax16(sT[1]));
      tmax = fmaxf(tmax, __shfl_xor(tmax, 32));
      if (__any(tmax > mr + 8.f)) {
        float mn = fmaxf(mr, tmax);
        float corr = fast_exp2(mr - mn);
        mr = mn;
        oT2[0] *= corr;
#pragma unroll
        for (int r = 0; r < 16; ++r) { oT[0][r] *= corr; oT[1][r] *= corr; }
      }
#pragma unroll
      for (int t = 0; t < 2; ++t)
#pragma unroll
        for (int r = 0; r < 16; ++r)
          sT[t][r] = fast_exp2(sT[t][r] - mr);

      // P^T -> B-operand frags: pB[2t+half] covers substep k-local 16(2t+half)..+15
      bf16x8 pB[4];
#pragma unroll
      for (int t = 0; t < 2; ++t)
#pragma unroll
        for (int half = 0; half < 2; ++half) {
          const int base = 8 * half;
          unsigned x0 = cvt_pk_bf16(sT[t][base + 0], sT[t][base + 1]);
          unsigned x1 = cvt_pk_bf16(sT[t][base + 2], sT[t][base + 3]);
          unsigned y0 = cvt_pk_bf16(sT[t][base + 4], sT[t][base + 5]);
          unsigned y1 = cvt_pk_bf16(sT[t][base + 6], sT[t][base + 7]);
          swap32(x0, y0);
          swap32(x1, y1);
          int4 packed = {(int)x0, (int)x1, (int)y0, (int)y1};
          pB[2 * t + half] = __builtin_bit_cast(bf16x8, packed);
        }
      // O^T += V^T * P^T (substep's 64-key slice); denominator on matrix pipe
#pragma unroll
      for (int dt = 0; dt < 2; ++dt) {
        int r = dt * 32 + l31;
#pragma unroll
        for (int mi = 0; mi < 4; ++mi) {
          int ch = (8 * sub + 2 * mi + H) ^ (r & 7);
          bf16x8 va = *reinterpret_cast<const bf16x8*>(&v_sh[cur][r * 128 + (ch << 3)]);
          oT[dt] = __builtin_amdgcn_mfma_f32_32x32x16_bf16(va, pB[mi], oT[dt], 0, 0, 0);
        }
      }
#pragma unroll
      for (int mi = 0; mi < 4; ++mi)
        oT2 = __builtin_amdgcn_mfma_f32_32x32x16_bf16(ones, pB[mi], oT2, 0, 0, 0);
    }
    __syncthreads();
  }
  // epilogue: lr = oT2[0] (every row of oT2 is the full colsum)
  float invl = 1.f / oT2[0];
#pragma unroll
  for (int dt = 0; dt < 2; ++dt)
#pragma unroll
    for (int rb = 0; rb < 4; ++rb) {
      us4 ov;
#pragma unroll
      for (int j = 0; j < 4; ++j) ov[j] = f2b(oT[dt][rb * 4 + j] * invl);
      *reinterpret_cast<us4*>(
          &O[((size_t)b * 2048 + tok) * 1024 + h * 64 + 32 * dt + 8 * rb + 4 * H]) = ov;
    }
#undef ATTN_STAGE
}

// ---------------------------------------------------------------- launch
extern "C" void kernel_launch(void* const* d_in, const int* in_sizes, int n_in,
                              void* d_out, int out_size, void* d_ws, size_t ws_size,
                              hipStream_t stream) {
  (void)in_sizes; (void)n_in; (void)out_size; (void)ws_size;
  const float* x      = (const float*)d_in[0];
  const float* w_qkv  = (const float*)d_in[1];
  const float* w_proj = (const float*)d_in[2];
  const float* b_proj = (const float*)d_in[3];
  const float* fcos   = (const float*)d_in[4];
  const float* fsin   = (const float*)d_in[5];
  float* out = (float*)d_out;
  char* ws = (char*)d_ws;

  unsigned short* x_bf     = (unsigned short*)(ws + 0);         // 8 MB
  unsigned short* wqkv_bf  = (unsigned short*)(ws + 8388608);   // 6 MB
  unsigned short* wproj_bf = (unsigned short*)(ws + 14680064);  // 2 MB
  unsigned short* q_bf     = (unsigned short*)(ws + 16777216);  // 8 MB
  unsigned short* k_bf     = (unsigned short*)(ws + 25165824);  // 8 MB
  unsigned short* vt_bf    = (unsigned short*)(ws + 33554432);  // 8 MB
  unsigned short* ao_bf    = (unsigned short*)(ws + 41943040);  // 8 MB (total 48 MB)

  cvt_all<<<4096, 256, 0, stream>>>(x, w_qkv, w_proj, x_bf, wqkv_bf, wproj_bf);
  gemm_qkv<<<dim3(24, 32), 256, 0, stream>>>(x_bf, wqkv_bf, fcos, fsin,
                                             q_bf, k_bf, vt_bf);
  attn_kern<<<512, 256, 0, stream>>>(q_bf, k_bf, vt_bf, ao_bf);
  gemm_proj<<<dim3(16, 32), 256, 0, stream>>>(ao_bf, wproj_bf, b_proj, out,
                                              4096, 1024, 1024);
}

// Round 18
// 108.032 us; speedup vs baseline: 1.0187x; 1.0187x over previous
//
#include <hip/hip_runtime.h>
#include <hip/hip_bf16.h>

// Problem constants: B=2, N=2048, C=1024, H=16, D=64  (head_dim)
// M = B*N = 4096 rows. qkv col layout: three*1024 + h*64 + d.

typedef __bf16 bf16x8 __attribute__((ext_vector_type(8)));
typedef float f32x4 __attribute__((ext_vector_type(4)));
typedef float f32x16 __attribute__((ext_vector_type(16)));
typedef unsigned short us8 __attribute__((ext_vector_type(8)));
typedef unsigned short us4 __attribute__((ext_vector_type(4)));

static __device__ __forceinline__ unsigned short f2b(float f) {
  __hip_bfloat16 h = __float2bfloat16(f);
  return __builtin_bit_cast(unsigned short, h);
}
static __device__ __forceinline__ float b2f(unsigned short u) {
  __hip_bfloat16 h = __builtin_bit_cast(__hip_bfloat16, u);
  return __bfloat162float(h);
}

#if __has_builtin(__builtin_amdgcn_exp2f)
static __device__ __forceinline__ float fast_exp2(float x) { return __builtin_amdgcn_exp2f(x); }
#else
static __device__ __forceinline__ float fast_exp2(float x) { return exp2f(x); }
#endif

// async global->LDS, 16B per lane. LDS dest = wave-uniform base + lane*16.
static __device__ __forceinline__ void async_copy16(void* lds, const void* g) {
  __builtin_amdgcn_global_load_lds(
      (const __attribute__((address_space(1))) void*)g,
      (__attribute__((address_space(3))) void*)lds, 16, 0, 0);
}

static __device__ __forceinline__ unsigned cvt_pk_bf16(float lo, float hi) {
  unsigned r;
  asm("v_cvt_pk_bf16_f32 %0, %1, %2" : "=v"(r) : "v"(lo), "v"(hi));
  return r;
}
static __device__ __forceinline__ void swap32(unsigned& x, unsigned& y) {
  asm("v_permlane32_swap_b32 %0, %1" : "+v"(x), "+v"(y));
}
static __device__ __forceinline__ float max3f(float a, float b, float c) {
  float d;
  asm("v_max3_f32 %0, %1, %2, %3" : "=v"(d) : "v"(a), "v"(b), "v"(c));
  return d;
}
// balanced max of 16 (5+2+1 ops, depth 3)
static __device__ __forceinline__ float vmax16(const f32x16& v) {
  float a = max3f(v[0], v[1], v[2]);
  float b = max3f(v[3], v[4], v[5]);
  float c = max3f(v[6], v[7], v[8]);
  float d = max3f(v[9], v[10], v[11]);
  float e = max3f(v[12], v[13], v[14]);
  float x = max3f(a, b, c);
  float y = max3f(d, e, v[15]);
  return fmaxf(x, y);
}
// balanced sum of 16 (15 adds, depth 4)
static __device__ __forceinline__ float vsum16(const f32x16& v) {
  float s0 = (v[0] + v[1]) + (v[2] + v[3]);
  float s1 = (v[4] + v[5]) + (v[6] + v[7]);
  float s2 = (v[8] + v[9]) + (v[10] + v[11]);
  float s3 = (v[12] + v[13]) + (v[14] + v[15]);
  return (s0 + s1) + (s2 + s3);
}

// ---------------------------------------------------------------- convert (all 3 inputs, 1 launch)
__global__ __launch_bounds__(256) void cvt_all(
    const float* __restrict__ x, const float* __restrict__ wqkv,
    const float* __restrict__ wproj, unsigned short* __restrict__ x_bf,
    unsigned short* __restrict__ wqkv_bf, unsigned short* __restrict__ wproj_bf) {
  int i = blockIdx.x * 256 + threadIdx.x;
  const float* src;
  unsigned short* dst;
  int off;
  if (i < 524288) {
    src = x; dst = x_bf; off = i;
  } else if (i < 917504) {
    src = wqkv; dst = wqkv_bf; off = i - 524288;
  } else {
    src = wproj; dst = wproj_bf; off = i - 917504;
  }
  const float4* p = reinterpret_cast<const float4*>(src) + (size_t)off * 2;
  float4 a = p[0], b = p[1];
  us8 v;
  v[0] = f2b(a.x); v[1] = f2b(a.y); v[2] = f2b(a.z); v[3] = f2b(a.w);
  v[4] = f2b(b.x); v[5] = f2b(b.y); v[6] = f2b(b.z); v[7] = f2b(b.w);
  reinterpret_cast<us8*>(dst)[off] = v;
}

// ---------------------------------------------------------------- QKV GEMM + LN + RoPE + V-transpose
// XCD-chunked block swizzle: 768 blocks, 96 consecutive tiles per XCD
// (= 4 complete A row-panels = 1MB A, L2-resident per XCD).
__global__ __launch_bounds__(256, 3) void gemm_qkv(
    const unsigned short* __restrict__ A,   // x_bf [4096][1024]
    const unsigned short* __restrict__ Bw,  // wqkv_bf [3072][1024]
    const float* __restrict__ fcos, const float* __restrict__ fsin,  // [2048][64]
    unsigned short* __restrict__ qo, unsigned short* __restrict__ ko,  // [32][2048][64]
    unsigned short* __restrict__ vt)  // [32][64][2048]
{
  __shared__ unsigned short a_sh[128 * 64];
  __shared__ unsigned short b_sh[128 * 64];
  const int tid = threadIdx.x;
  const int lane = tid & 63;
  const int w = tid >> 6;
  const int wr = w >> 1, wc = w & 1;
  const int l15 = lane & 15, l4 = lane >> 4;
  const int lin = blockIdx.y * 24 + blockIdx.x;
  const int swz = (lin & 7) * 96 + (lin >> 3);  // bijective (768 = 8*96)
  const int m0 = (swz / 24) * 128;
  const int n0 = (swz % 24) * 128;
  const int r8 = lane >> 3, c8 = lane & 7;
  const int K = 1024;

  f32x4 acc[4][4] = {};

  for (int k0 = 0; k0 < K; k0 += 64) {
#pragma unroll
    for (int p = 0; p < 8; ++p) {
      int s = p * 4 + w;
      if (s < 16) {
        int row = s * 8 + r8;
        async_copy16(&a_sh[s * 512],
                     &A[(size_t)(m0 + row) * K + k0 + ((c8 ^ (row & 7)) << 3)]);
      } else {
        int s2 = s - 16;
        int row = s2 * 8 + r8;
        async_copy16(&b_sh[s2 * 512],
                     &Bw[(size_t)(n0 + row) * K + k0 + ((c8 ^ (row & 7)) << 3)]);
      }
    }
    __syncthreads();
#pragma unroll
    for (int kk = 0; kk < 2; ++kk) {
      bf16x8 af[4], bfr[4];
#pragma unroll
      for (int mf = 0; mf < 4; ++mf) {
        int r = wr * 64 + mf * 16 + l15;
        af[mf] = *reinterpret_cast<const bf16x8*>(
            &a_sh[r * 64 + (((kk * 4 + l4) ^ (r & 7)) << 3)]);
      }
#pragma unroll
      for (int nf = 0; nf < 4; ++nf) {
        int r = wc * 64 + nf * 16 + l15;
        bfr[nf] = *reinterpret_cast<const bf16x8*>(
            &b_sh[r * 64 + (((kk * 4 + l4) ^ (r & 7)) << 3)]);
      }
#pragma unroll
      for (int mf = 0; mf < 4; ++mf)
#pragma unroll
        for (int nf = 0; nf < 4; ++nf)
          acc[mf][nf] = __builtin_amdgcn_mfma_f32_16x16x32_bf16(af[mf], bfr[nf], acc[mf][nf], 0, 0, 0);
    }
    __syncthreads();
  }

  // ---- fused epilogue ----
  const int colbase = n0 + wc * 64;       // head-aligned (64 | colbase)
  const int three = colbase >> 10;        // uniform per wave
  const int hh = (colbase >> 6) & 15;
  const int b_ = m0 >> 11;                // uniform per block (128 | 2048)
  const int nbase = (m0 & 2047) + wr * 64;
  unsigned short* ep = ((w < 2) ? a_sh : b_sh) + (w & 1) * 4096;  // 8KB/wave
  const int cch = lane & 7, rb2 = lane >> 3;

  if (three < 2) {
    const float sc = three ? 1.f : 0.18033688011112042f;  // q: D^-0.5 * log2(e)
#pragma unroll
    for (int mf = 0; mf < 4; ++mf) {
#pragma unroll
      for (int j = 0; j < 4; ++j) {
        float a0 = acc[mf][0][j], a1 = acc[mf][1][j];
        float a2 = acc[mf][2][j], a3 = acc[mf][3][j];
        float s1 = (a0 + a1) + (a2 + a3);
        float s2 = (a0 * a0 + a1 * a1) + (a2 * a2 + a3 * a3);
#pragma unroll
        for (int off = 8; off; off >>= 1) {
          s1 += __shfl_xor(s1, off);
          s2 += __shfl_xor(s2, off);
        }
        float mu = s1 * (1.f / 64.f);
        float inv = rsqrtf(s2 * (1.f / 64.f) - mu * mu + 1e-6f);
        int rloc = mf * 16 + l4 * 4 + j;  // row within wave block (0..63)
        int n = nbase + rloc;
        const float* cp = &fcos[(size_t)n * 64];
        const float* sp = &fsin[(size_t)n * 64];
#pragma unroll
        for (int nf = 0; nf < 4; ++nf) {
          int d = nf * 16 + l15;
          float tt = (acc[mf][nf][j] - mu) * inv;
          float tp = (acc[mf][nf ^ 2][j] - mu) * inv;  // partner d^32
          float r = sc * (tt * cp[d] + ((nf < 2) ? -tp : tp) * sp[d]);
          ep[rloc * 64 + ((((d >> 3) ^ (rloc & 7)) << 3) | (d & 7))] = f2b(r);
        }
      }
    }
    unsigned short* dst =
        (three ? ko : qo) + (size_t)(b_ * 16 + hh) * 2048 * 64;
#pragma unroll
    for (int i = 0; i < 8; ++i) {
      int row = i * 8 + rb2;
      us8 vd = *reinterpret_cast<const us8*>(
          &ep[row * 64 + ((cch ^ (row & 7)) << 3)]);
      *reinterpret_cast<us8*>(&dst[(size_t)(nbase + row) * 64 + cch * 8]) = vd;
    }
  } else {
    // v: stash as [d][n_local] (transpose), then coalesced store to vt[bh][d][n]
#pragma unroll
    for (int mf = 0; mf < 4; ++mf)
#pragma unroll
      for (int nf = 0; nf < 4; ++nf) {
        int d = nf * 16 + l15;
#pragma unroll
        for (int j = 0; j < 4; ++j) {
          int nl = mf * 16 + l4 * 4 + j;
          ep[d * 64 + ((((nl >> 3) ^ (d & 7)) << 3) | (nl & 7))] =
              f2b(acc[mf][nf][j]);
        }
      }
    unsigned short* dst = vt + (size_t)(b_ * 16 + hh) * 64 * 2048;
#pragma unroll
    for (int i = 0; i < 8; ++i) {
      int d = i * 8 + rb2;
      us8 vd = *reinterpret_cast<const us8*>(
          &ep[d * 64 + ((cch ^ (d & 7)) << 3)]);
      *reinterpret_cast<us8*>(&dst[(size_t)d * 2048 + nbase + cch * 8]) = vd;
    }
  }
}

// ---------------------------------------------------------------- proj GEMM
// 128x64 tile (grid 16x32 = 512 blocks = 2/CU). 4 waves 2x2; acc[4][2].
__global__ __launch_bounds__(256, 2) void gemm_proj(
    const unsigned short* __restrict__ A, const unsigned short* __restrict__ Bw,
    const float* __restrict__ bias, float* __restrict__ Cout,
    int M, int Nn, int K) {
  __shared__ unsigned short a_sh[128 * 64];
  __shared__ unsigned short b_sh[64 * 64];
  const int tid = threadIdx.x;
  const int lane = tid & 63;
  const int w = tid >> 6;
  const int wr = w >> 1, wc = w & 1;
  const int l15 = lane & 15, l4 = lane >> 4;
  const int m0 = blockIdx.y * 128;
  const int n0 = blockIdx.x * 64;
  const int r8 = lane >> 3, c8 = lane & 7;

  f32x4 acc[4][2] = {};

  for (int k0 = 0; k0 < K; k0 += 64) {
#pragma unroll
    for (int p = 0; p < 6; ++p) {
      int s = p * 4 + w;
      if (s < 16) {
        int row = s * 8 + r8;
        async_copy16(&a_sh[s * 512],
                     &A[(size_t)(m0 + row) * K + k0 + ((c8 ^ (row & 7)) << 3)]);
      } else {
        int s2 = s - 16;
        int row = s2 * 8 + r8;
        async_copy16(&b_sh[s2 * 512],
                     &Bw[(size_t)(n0 + row) * K + k0 + ((c8 ^ (row & 7)) << 3)]);
      }
    }
    __syncthreads();
#pragma unroll
    for (int kk = 0; kk < 2; ++kk) {
      bf16x8 af[4], bfr[2];
#pragma unroll
      for (int mf = 0; mf < 4; ++mf) {
        int r = wr * 64 + mf * 16 + l15;
        af[mf] = *reinterpret_cast<const bf16x8*>(
            &a_sh[r * 64 + (((kk * 4 + l4) ^ (r & 7)) << 3)]);
      }
#pragma unroll
      for (int nf = 0; nf < 2; ++nf) {
        int r = wc * 32 + nf * 16 + l15;
        bfr[nf] = *reinterpret_cast<const bf16x8*>(
            &b_sh[r * 64 + (((kk * 4 + l4) ^ (r & 7)) << 3)]);
      }
#pragma unroll
      for (int mf = 0; mf < 4; ++mf)
#pragma unroll
        for (int nf = 0; nf < 2; ++nf)
          acc[mf][nf] = __builtin_amdgcn_mfma_f32_16x16x32_bf16(af[mf], bfr[nf], acc[mf][nf], 0, 0, 0);
    }
    __syncthreads();
  }
#pragma unroll
  for (int mf = 0; mf < 4; ++mf)
#pragma unroll
    for (int nf = 0; nf < 2; ++nf) {
      int col = n0 + wc * 32 + nf * 16 + l15;
#pragma unroll
      for (int j = 0; j < 4; ++j) {
        int row = m0 + wr * 64 + mf * 16 + l4 * 4 + j;
        Cout[(size_t)row * Nn + col] = acc[mf][nf][j] + bias[col];
      }
    }
}

// ---------------------------------------------------------------- attention
// R16 proven config (52.0 us): swapped-QK^T 32x32, KVBLK=128 dbuf (64KB),
// (256,2), defer-max, two 64-key sub-steps, kt-unroll-2 (addresses hoist).
// R17's denominator-on-MFMA regressed (matrix pipe became critical) — the
// VALU tsum returns, but as a balanced tree (same adds, depth 5 not 32).
__global__ __launch_bounds__(256, 2) void attn_kern(
    const unsigned short* __restrict__ Q,   // [B*H][2048][64]  (pre-scaled)
    const unsigned short* __restrict__ Kk,  // [B*H][2048][64]
    const unsigned short* __restrict__ Vt,  // [B*H][64][2048]
    unsigned short* __restrict__ O)         // [B][2048][1024]
{
  __shared__ unsigned short k_sh[2][128 * 64];
  __shared__ unsigned short v_sh[2][64 * 128];
  const int tid = threadIdx.x;
  const int lane = tid & 63;
  const int w = tid >> 6;
  const int l31 = lane & 31;
  const int H = lane >> 5;
  const int bid = blockIdx.x;
  const int wid = (bid & 7) * 64 + (bid >> 3);  // XCD swizzle: 4 bh per XCD
  const int qt = wid & 15;
  const int bh = wid >> 4;
  const int h = bh & 15, b = bh >> 4;
  const unsigned short* qb = Q + (size_t)bh * 2048 * 64;
  const unsigned short* kb = Kk + (size_t)bh * 2048 * 64;
  const unsigned short* vb = Vt + (size_t)bh * 64 * 2048;
  const int tok = qt * 128 + w * 32 + l31;

  // Q B-frags: lane holds Q[tok][c*16 + H*8 .. +7]
  bf16x8 qf[4];
#pragma unroll
  for (int c = 0; c < 4; ++c)
    qf[c] = *reinterpret_cast<const bf16x8*>(&qb[(size_t)tok * 64 + c * 16 + H * 8]);

  f32x16 oT[2] = {};
  float mr = -1e30f, lr = 0.f;  // lr = half-row sum; combined at epilogue

  const int r8 = lane >> 3, cc8 = lane & 7;    // K staging
  const int r4 = lane >> 4, cc16 = lane & 15;  // V staging
  // stage one 128-key tile: K 16 segs (8 rows x 128B), V^T 16 segs (4 rows x 256B)
#define ATTN_STAGE(KT, BUF)                                                           \
  {                                                                                   \
    _Pragma("unroll") for (int p = 0; p < 8; ++p) {                                   \
      int sseg = p * 4 + w;                                                           \
      if (sseg < 16) {                                                                \
        int row = sseg * 8 + r8;                                                      \
        async_copy16(&k_sh[BUF][sseg * 512],                                          \
                     &kb[(size_t)((KT) * 128 + row) * 64 + ((cc8 ^ (row & 7)) << 3)]);   \
      } else {                                                                        \
        int s2 = sseg - 16;                                                           \
        int row = s2 * 4 + r4;                                                        \
        async_copy16(&v_sh[BUF][s2 * 512],                                            \
                     &vb[(size_t)row * 2048 + (KT) * 128 + ((cc16 ^ (row & 7)) << 3)]);  \
      }                                                                               \
    }                                                                                 \
  }

  ATTN_STAGE(0, 0);
  __syncthreads();

#pragma unroll 2
  for (int kt = 0; kt < 16; ++kt) {
    const int cur = kt & 1;  // compile-time under unroll-2 -> addresses hoist
    if (kt < 15) ATTN_STAGE(kt + 1, cur ^ 1);

#pragma unroll
    for (int sub = 0; sub < 2; ++sub) {
      // S^T[k][q] for this 64-key substep, accumulate over d (4 chunks of 16)
      f32x16 sT[2] = {};
#pragma unroll
      for (int c = 0; c < 4; ++c) {
        int ch0 = 2 * c + H;
#pragma unroll
        for (int t = 0; t < 2; ++t) {
          int r = (sub * 2 + t) * 32 + l31;
          bf16x8 ka = *reinterpret_cast<const bf16x8*>(
              &k_sh[cur][r * 64 + ((ch0 ^ (r & 7)) << 3)]);
          sT[t] = __builtin_amdgcn_mfma_f32_32x32x16_bf16(ka, qf[c], sT[t], 0, 0, 0);
        }
      }
      // online softmax (exp2 domain); defer-rescale THR=8
      float tmax = fmaxf(vmax16(sT[0]), vmax16(sT[1]));
      tmax = fmaxf(tmax, __shfl_xor(tmax, 32));
      if (__any(tmax > mr + 8.f)) {
        float mn = fmaxf(mr, tmax);
        float corr = fast_exp2(mr - mn);
        mr = mn;
        lr *= corr;
#pragma unroll
        for (int r = 0; r < 16; ++r) { oT[0][r] *= corr; oT[1][r] *= corr; }
      }
#pragma unroll
      for (int t = 0; t < 2; ++t)
#pragma unroll
        for (int r = 0; r < 16; ++r)
          sT[t][r] = fast_exp2(sT[t][r] - mr);
      lr += vsum16(sT[0]) + vsum16(sT[1]);  // balanced tree, depth 5

      // P^T -> B-operand frags: pB[2t+half] covers substep k-local 16(2t+half)..+15
      bf16x8 pB[4];
#pragma unroll
      for (int t = 0; t < 2; ++t)
#pragma unroll
        for (int half = 0; half < 2; ++half) {
          const int base = 8 * half;
          unsigned x0 = cvt_pk_bf16(sT[t][base + 0], sT[t][base + 1]);
          unsigned x1 = cvt_pk_bf16(sT[t][base + 2], sT[t][base + 3]);
          unsigned y0 = cvt_pk_bf16(sT[t][base + 4], sT[t][base + 5]);
          unsigned y1 = cvt_pk_bf16(sT[t][base + 6], sT[t][base + 7]);
          swap32(x0, y0);
          swap32(x1, y1);
          int4 packed = {(int)x0, (int)x1, (int)y0, (int)y1};
          pB[2 * t + half] = __builtin_bit_cast(bf16x8, packed);
        }
      // O^T += V^T * P^T (substep's 64-key slice)
#pragma unroll
      for (int dt = 0; dt < 2; ++dt) {
        int r = dt * 32 + l31;
#pragma unroll
        for (int mi = 0; mi < 4; ++mi) {
          int ch = (8 * sub + 2 * mi + H) ^ (r & 7);
          bf16x8 va = *reinterpret_cast<const bf16x8*>(&v_sh[cur][r * 128 + (ch << 3)]);
          oT[dt] = __builtin_amdgcn_mfma_f32_32x32x16_bf16(va, pB[mi], oT[dt], 0, 0, 0);
        }
      }
    }
    __syncthreads();
  }
  // epilogue: combine half-row sums, then O[b, tok, h*64 + d]
  lr += __shfl_xor(lr, 32);
  float invl = 1.f / lr;
#pragma unroll
  for (int dt = 0; dt < 2; ++dt)
#pragma unroll
    for (int rb = 0; rb < 4; ++rb) {
      us4 ov;
#pragma unroll
      for (int j = 0; j < 4; ++j) ov[j] = f2b(oT[dt][rb * 4 + j] * invl);
      *reinterpret_cast<us4*>(
          &O[((size_t)b * 2048 + tok) * 1024 + h * 64 + 32 * dt + 8 * rb + 4 * H]) = ov;
    }
#undef ATTN_STAGE
}

// ---------------------------------------------------------------- launch
extern "C" void kernel_launch(void* const* d_in, const int* in_sizes, int n_in,
                              void* d_out, int out_size, void* d_ws, size_t ws_size,
                              hipStream_t stream) {
  (void)in_sizes; (void)n_in; (void)out_size; (void)ws_size;
  const float* x      = (const float*)d_in[0];
  const float* w_qkv  = (const float*)d_in[1];
  const float* w_proj = (const float*)d_in[2];
  const float* b_proj = (const float*)d_in[3];
  const float* fcos   = (const float*)d_in[4];
  const float* fsin   = (const float*)d_in[5];
  float* out = (float*)d_out;
  char* ws = (char*)d_ws;

  unsigned short* x_bf     = (unsigned short*)(ws + 0);         // 8 MB
  unsigned short* wqkv_bf  = (unsigned short*)(ws + 8388608);   // 6 MB
  unsigned short* wproj_bf = (unsigned short*)(ws + 14680064);  // 2 MB
  unsigned short* q_bf     = (unsigned short*)(ws + 16777216);  // 8 MB
  unsigned short* k_bf     = (unsigned short*)(ws + 25165824);  // 8 MB
  unsigned short* vt_bf    = (unsigned short*)(ws + 33554432);  // 8 MB
  unsigned short* ao_bf    = (unsigned short*)(ws + 41943040);  // 8 MB (total 48 MB)

  cvt_all<<<4096, 256, 0, stream>>>(x, w_qkv, w_proj, x_bf, wqkv_bf, wproj_bf);
  gemm_qkv<<<dim3(24, 32), 256, 0, stream>>>(x_bf, wqkv_bf, fcos, fsin,
                                             q_bf, k_bf, vt_bf);
  attn_kern<<<512, 256, 0, stream>>>(q_bf, k_bf, vt_bf, ao_bf);
  gemm_proj<<<dim3(16, 32), 256, 0, stream>>>(ao_bf, wproj_bf, b_proj, out,
                                              4096, 1024, 1024);
}